// Round 6
// baseline (842.086 us; speedup 1.0000x reference)
//
#include <hip/hip_runtime.h>

typedef __attribute__((ext_vector_type(8))) short short8;
typedef __attribute__((ext_vector_type(4))) float f32x4;

#define NPTS 131072
#define NOFF 125
#define KERN_USH (NOFF * 16384)   // 2,048,000 bf16 elements

__device__ int g_isf32[4];                                   // per-input f32 flag
__device__ __align__(16) unsigned short g_x[NPTS * 128];     // x converted to bf16 (f32 case)
__device__ __align__(16) unsigned short g_kern[KERN_USH + 128]; // packed kern + zero row

__device__ __forceinline__ float bf2f(unsigned short u) {
  unsigned int v = ((unsigned int)u) << 16;
  return __builtin_bit_cast(float, v);
}
__device__ __forceinline__ unsigned short f2bf(float f) {
  unsigned int x = __builtin_bit_cast(unsigned int, f);
  x += 0x7fffu + ((x >> 16) & 1u);
  return (unsigned short)(x >> 16);
}
__device__ __forceinline__ float rdf(const void* p, int i, int isf32) {
  return isf32 ? ((const float*)p)[i] : bf2f(((const unsigned short*)p)[i]);
}

// direct global->LDS, 16B per lane; LDS dest = wave-uniform base + lane*16
#define GLD16(gp, lp)                                                        \
  __builtin_amdgcn_global_load_lds(                                          \
      (const __attribute__((address_space(1))) unsigned int*)(gp),           \
      (__attribute__((address_space(3))) unsigned int*)(lp), 16, 0, 0)

// --------------------------------------------------------------------------
// Dtype detection (even-indexed ushorts of true bf16 N(0,1) are ~100% in
// [1e-8, 64]; f32-as-bf16 mantissa halves are ~13%).
// --------------------------------------------------------------------------
__global__ __launch_bounds__(64) void k_detect(const unsigned short* x,
                                               const unsigned short* w,
                                               const unsigned short* s,
                                               const unsigned short* v) {
  const unsigned short* ptrs[4] = {x, w, s, v};
  const int l = threadIdx.x;
  #pragma unroll
  for (int i = 0; i < 4; ++i) {
    const unsigned short u = ptrs[i][2 * l];
    const float a = fabsf(bf2f(u));
    const int good = (u == 0) || (a >= 1e-8f && a <= 64.0f);
    const unsigned long long m = __ballot(good);
    if (l == 0) g_isf32[i] = (__popcll(m) < 45) ? 1 : 0;
  }
}

__global__ __launch_bounds__(256) void k_convx(const void* xin) {
  if (!g_isf32[0]) return;
  const float* xf = (const float*)xin;
  const int t = blockIdx.x * 256 + threadIdx.x;
  short8 o;
  #pragma unroll
  for (int j = 0; j < 8; ++j) o[j] = (short)f2bf(xf[t * 8 + j]);
  *(short8*)(&g_x[t * 8]) = o;
}

// --------------------------------------------------------------------------
// Kernel-tensor generation: (125,128,128) bf16, fragment-packed for MFMA-B.
// packed[koff*16384 + ((kb*8+nt)*64 + l)*8 + t] =
//   kern[koff][ i = kb*32 + (l>>4)*8 + t ][ j = nt*16 + (l&15) ]
// Self-connection folded into koff==62 (offset (0,0,0)).
// --------------------------------------------------------------------------
__global__ __launch_bounds__(256) void gen_kern(const void* __restrict__ weight,
                                                const void* __restrict__ wscs,
                                                const void* __restrict__ wscv) {
  __shared__ float W[4][32][32];
  __shared__ float embs[5];
  const int wf = g_isf32[1], sf = g_isf32[2], vf = g_isf32[3];
  const int koff = blockIdx.x;
  const int tid = threadIdx.x;
  const int xi = koff % 5, yi = (koff / 5) % 5, zi = koff / 25;
  const float lx = (float)(xi - 2), ly = (float)(yi - 2), lz = (float)(zi - 2);
  const float nrm = sqrtf(lx*lx + ly*ly + lz*lz);
  if (tid < 5) {
    const float step = 2.5f / 6.0f;
    const float vb = step * (float)(tid + 1);
    const float d = (nrm - vb) / step;
    float e = 0.0f;
    if (fabsf(d) < 1.0f) {
      float ds = fminf(fmaxf(d, -1.0f + 1e-6f), 1.0f - 1e-6f);
      e = 1.14136f * expf(2.0f - 1.0f/(1.0f + ds) - 1.0f/(1.0f - ds));
    }
    embs[tid] = e;
  }
  __syncthreads();
  float* Wf = &W[0][0][0];
  for (int m = tid; m < 4096; m += 256) {
    float s = 0.0f;
    #pragma unroll
    for (int b = 0; b < 5; ++b) s += embs[b] * rdf(weight, b*4096 + m, wf);
    Wf[m] = s * (1.0f / 125.0f);
  }
  __syncthreads();
  const float invn = (nrm > 0.0f) ? 1.0f / nrm : 0.0f;
  const float s3 = 1.7320508075688772f;
  const float Y1v0 = s3 * ly * invn;
  const float Y1v1 = s3 * lz * invn;
  const float Y1v2 = s3 * lx * invn;
  const float c  = 0.125f;
  const float cs = 0.125f / s3;
  const bool center = (koff == 62);
  const float inv = 0.17677669529663687f;  // 1/sqrt(32)
  for (int p = tid; p < 16384; p += 256) {
    const int t = p & 7;
    const int l = (p >> 3) & 63;
    const int f = p >> 9;
    const int kb = f >> 3, nt = f & 7;
    const int i = kb*32 + (l >> 4)*8 + t;
    const int j = nt*16 + (l & 15);
    float val;
    if (i < 32) {
      if (j < 32) {
        val = c * W[0][i][j];
        if (center) val += inv * rdf(wscs, i*32 + j, sf);
      } else {
        const int wq = (j - 32) / 3, kk = (j - 32) % 3;
        const float yv = (kk == 0) ? Y1v0 : ((kk == 1) ? Y1v1 : Y1v2);
        val = c * W[1][i][wq] * yv;
      }
    } else {
      const int u = (i - 32) / 3, ii = (i - 32) % 3;
      const float yvi = (ii == 0) ? Y1v0 : ((ii == 1) ? Y1v1 : Y1v2);
      if (j < 32) {
        val = cs * W[3][u][j] * yvi;
      } else {
        const int wq = (j - 32) / 3, kk = (j - 32) % 3;
        val = (ii == kk) ? c * W[2][u][wq] : 0.0f;
        if (center && ii == kk) val += inv * rdf(wscv, u*32 + wq, vf);
      }
    }
    g_kern[koff * 16384 + p] = f2bf(val);
  }
  if (koff == 0 && tid < 128) g_kern[KERN_USH + tid] = 0;  // zero row (idx==N)
}

// --------------------------------------------------------------------------
// Main conv: 1024 WGs x 256 thr (4 waves) -> 4 blocks/CU (LDS 32KB each,
// VGPR<=128 -> 16 waves/CU). Wave = 64 points x 64 cols; block = 128 pts
// x 128 cols. Fragment-sparse act-gating. B single-buffer via
// global_load_lds, 2 barriers/ko. Coalesced epilogue via LDS bounce.
// --------------------------------------------------------------------------
__global__ __launch_bounds__(256, 4) void conv_main(
    const unsigned short* __restrict__ xfeat,
    const int* __restrict__ nidx,
    void* __restrict__ out)
{
  __shared__ __align__(16) unsigned short Blds[16384];  // 32 KB, single buffer
  const int of32 = g_isf32[0];
  const unsigned short* xs = of32 ? g_x : xfeat;
  const int tid = threadIdx.x;
  const int wv = tid >> 6;
  const int l  = tid & 63;
  const int lr = l & 15;
  const int lk = l >> 4;
  const int ph = wv >> 1;          // point-half (0/1)
  const int ch = wv & 1;           // column-half (0/1)
  const int m0 = blockIdx.x * 128 + ph * 64;

  f32x4 acc[4][4];
  #pragma unroll
  for (int i = 0; i < 4; ++i)
    #pragma unroll
    for (int j = 0; j < 4; ++j) acc[i][j] = (f32x4)0.0f;

  const unsigned short* zrow = g_kern + KERN_USH;

  // prologue: indices for ko=0
  int idxc[4], idxn[4];
  {
    const int* ip = nidx + m0;
    #pragma unroll
    for (int mt = 0; mt < 4; ++mt) idxc[mt] = ip[mt*16 + lr];
  }

  for (int ko = 0; ko < NOFF; ++ko) {
    const bool hn = (ko + 1 < NOFF);

    // stage B(ko) into the single buffer (prev compute finished at loop-end barrier)
    {
      const unsigned short* s = g_kern + ko * 16384 + tid*8;
      unsigned short* d = &Blds[tid*8];
      #pragma unroll
      for (int c = 0; c < 8; ++c) GLD16(s + c*2048, d + c*2048);
    }
    // prefetch indices for ko+1 (used next iteration)
    if (hn) {
      const int* ip = nidx + (size_t)(ko + 1) * NPTS + m0;
      #pragma unroll
      for (int mt = 0; mt < 4; ++mt) idxn[mt] = ip[mt*16 + lr];
    }

    // activity + row pointers for this ko; issue kb0/kb1 gathers pre-barrier
    bool act[4];
    const unsigned short* rp[4];
    #pragma unroll
    for (int mt = 0; mt < 4; ++mt) {
      const bool valid = (unsigned)idxc[mt] < (unsigned)NPTS;
      act[mt] = __any(valid);
      rp[mt] = valid ? (xs + (size_t)idxc[mt] * 128 + lk*8) : (zrow + lk*8);
    }
    short8 a[2][4];
    #pragma unroll
    for (int mt = 0; mt < 4; ++mt)
      if (act[mt]) a[0][mt] = *(const short8*)(rp[mt]);
    #pragma unroll
    for (int mt = 0; mt < 4; ++mt)
      if (act[mt]) a[1][mt] = *(const short8*)(rp[mt] + 32);

    __syncthreads();   // B staged + early A drained

    #pragma unroll
    for (int kb = 0; kb < 4; ++kb) {
      short8 b[4];
      #pragma unroll
      for (int nt = 0; nt < 4; ++nt)
        b[nt] = *(const short8*)(&Blds[((kb*8 + ch*4 + nt)*64 + l)*8]);
      #pragma unroll
      for (int mt = 0; mt < 4; ++mt) {
        if (act[mt]) {
          #pragma unroll
          for (int nt = 0; nt < 4; ++nt)
            acc[mt][nt] = __builtin_amdgcn_mfma_f32_16x16x32_bf16(
                a[kb & 1][mt], b[nt], acc[mt][nt], 0, 0, 0);
        }
      }
      if (kb < 2) {   // refill consumed slot with kb+2
        #pragma unroll
        for (int mt = 0; mt < 4; ++mt)
          if (act[mt]) a[kb & 1][mt] = *(const short8*)(rp[mt] + (kb + 2)*32);
      }
    }

    #pragma unroll
    for (int mt = 0; mt < 4; ++mt) idxc[mt] = idxn[mt];
    __syncthreads();   // all waves done reading B before next stage
  }

  // epilogue
  if (of32) {
    float* of = (float*)out;
    #pragma unroll
    for (int mt = 0; mt < 4; ++mt)
      #pragma unroll
      for (int nt = 0; nt < 4; ++nt)
        #pragma unroll
        for (int r = 0; r < 4; ++r)
          of[(size_t)(m0 + mt*16 + lk*4 + r) * 128 + ch*64 + nt*16 + lr] =
              acc[mt][nt][r];
  } else {
    // block-wide LDS bounce (XOR-swizzled), then coalesced 16B stores
    #pragma unroll
    for (int mt = 0; mt < 4; ++mt)
      #pragma unroll
      for (int nt = 0; nt < 4; ++nt)
        #pragma unroll
        for (int r = 0; r < 4; ++r) {
          const int row = ph*64 + mt*16 + lk*4 + r;    // 0..127 local
          const int ush = ch*64 + nt*16 + lr;          // 0..127 in-row
          Blds[row*128 + (ush ^ ((row & 7) << 3))] = f2bf(acc[mt][nt][r]);
        }
    __syncthreads();
    unsigned short* ob = (unsigned short*)out;
    const int row = tid >> 1;
    #pragma unroll
    for (int it = 0; it < 8; ++it) {
      const int ub = (tid & 1)*64 + it*8;
      const short8 v = *(const short8*)(&Blds[row*128 + (ub ^ ((row & 7) << 3))]);
      *(short8*)(&ob[(size_t)(blockIdx.x*128 + row) * 128 + ub]) = v;
    }
  }
}

extern "C" void kernel_launch(void* const* d_in, const int* in_sizes, int n_in,
                              void* d_out, int out_size, void* d_ws, size_t ws_size,
                              hipStream_t stream) {
  const unsigned short* xfeat  = (const unsigned short*)d_in[0];
  const void*           weight = d_in[1];
  const void*           wscs   = d_in[2];
  const void*           wscv   = d_in[3];
  const int*            nidx   = (const int*)d_in[4];

  hipLaunchKernelGGL(k_detect, dim3(1), dim3(64), 0, stream,
                     (const unsigned short*)d_in[0], (const unsigned short*)d_in[1],
                     (const unsigned short*)d_in[2], (const unsigned short*)d_in[3]);
  hipLaunchKernelGGL(k_convx, dim3(NPTS * 128 / (256 * 8)), dim3(256), 0, stream, d_in[0]);
  hipLaunchKernelGGL(gen_kern, dim3(NOFF), dim3(256), 0, stream, weight, wscs, wscv);
  hipLaunchKernelGGL(conv_main, dim3(NPTS / 128), dim3(256), 0, stream,
                     xfeat, nidx, d_out);
}

// Round 7
// 353.444 us; speedup vs baseline: 2.3825x; 2.3825x over previous
//
#include <hip/hip_runtime.h>

typedef __attribute__((ext_vector_type(8))) short short8;
typedef __attribute__((ext_vector_type(4))) float f32x4;

#define NPTS 131072
#define NOFF 125
#define KERN_USH (NOFF * 16384)   // 2,048,000 bf16 elements

__device__ int g_isf32[4];                                   // per-input f32 flag
__device__ __align__(16) unsigned short g_x[NPTS * 128];     // x converted to bf16 (f32 case)
__device__ __align__(16) unsigned short g_kern[KERN_USH + 128]; // packed kern + zero row

__device__ __forceinline__ float bf2f(unsigned short u) {
  unsigned int v = ((unsigned int)u) << 16;
  return __builtin_bit_cast(float, v);
}
__device__ __forceinline__ unsigned short f2bf(float f) {
  unsigned int x = __builtin_bit_cast(unsigned int, f);
  x += 0x7fffu + ((x >> 16) & 1u);
  return (unsigned short)(x >> 16);
}
__device__ __forceinline__ float rdf(const void* p, int i, int isf32) {
  return isf32 ? ((const float*)p)[i] : bf2f(((const unsigned short*)p)[i]);
}

// direct global->LDS, 16B per lane; LDS dest = wave-uniform base + lane*16
#define GLD16(gp, lp)                                                        \
  __builtin_amdgcn_global_load_lds(                                          \
      (const __attribute__((address_space(1))) unsigned int*)(gp),           \
      (__attribute__((address_space(3))) unsigned int*)(lp), 16, 0, 0)

// --------------------------------------------------------------------------
// Dtype detection (even-indexed ushorts of true bf16 N(0,1) are ~100% in
// [1e-8, 64]; f32-as-bf16 mantissa halves are ~13%).
// --------------------------------------------------------------------------
__global__ __launch_bounds__(64) void k_detect(const unsigned short* x,
                                               const unsigned short* w,
                                               const unsigned short* s,
                                               const unsigned short* v) {
  const unsigned short* ptrs[4] = {x, w, s, v};
  const int l = threadIdx.x;
  #pragma unroll
  for (int i = 0; i < 4; ++i) {
    const unsigned short u = ptrs[i][2 * l];
    const float a = fabsf(bf2f(u));
    const int good = (u == 0) || (a >= 1e-8f && a <= 64.0f);
    const unsigned long long m = __ballot(good);
    if (l == 0) g_isf32[i] = (__popcll(m) < 45) ? 1 : 0;
  }
}

__global__ __launch_bounds__(256) void k_convx(const void* xin) {
  if (!g_isf32[0]) return;
  const float* xf = (const float*)xin;
  const int t = blockIdx.x * 256 + threadIdx.x;
  short8 o;
  #pragma unroll
  for (int j = 0; j < 8; ++j) o[j] = (short)f2bf(xf[t * 8 + j]);
  *(short8*)(&g_x[t * 8]) = o;
}

// --------------------------------------------------------------------------
// Kernel-tensor generation: (125,128,128) bf16, fragment-packed for MFMA-B.
// packed[koff*16384 + ((kb*8+nt)*64 + l)*8 + t] =
//   kern[koff][ i = kb*32 + (l>>4)*8 + t ][ j = nt*16 + (l&15) ]
// Self-connection folded into koff==62 (offset (0,0,0)).
// --------------------------------------------------------------------------
__global__ __launch_bounds__(256) void gen_kern(const void* __restrict__ weight,
                                                const void* __restrict__ wscs,
                                                const void* __restrict__ wscv) {
  __shared__ float W[4][32][32];
  __shared__ float embs[5];
  const int wf = g_isf32[1], sf = g_isf32[2], vf = g_isf32[3];
  const int koff = blockIdx.x;
  const int tid = threadIdx.x;
  const int xi = koff % 5, yi = (koff / 5) % 5, zi = koff / 25;
  const float lx = (float)(xi - 2), ly = (float)(yi - 2), lz = (float)(zi - 2);
  const float nrm = sqrtf(lx*lx + ly*ly + lz*lz);
  if (tid < 5) {
    const float step = 2.5f / 6.0f;
    const float vb = step * (float)(tid + 1);
    const float d = (nrm - vb) / step;
    float e = 0.0f;
    if (fabsf(d) < 1.0f) {
      float ds = fminf(fmaxf(d, -1.0f + 1e-6f), 1.0f - 1e-6f);
      e = 1.14136f * expf(2.0f - 1.0f/(1.0f + ds) - 1.0f/(1.0f - ds));
    }
    embs[tid] = e;
  }
  __syncthreads();
  float* Wf = &W[0][0][0];
  for (int m = tid; m < 4096; m += 256) {
    float s = 0.0f;
    #pragma unroll
    for (int b = 0; b < 5; ++b) s += embs[b] * rdf(weight, b*4096 + m, wf);
    Wf[m] = s * (1.0f / 125.0f);
  }
  __syncthreads();
  const float invn = (nrm > 0.0f) ? 1.0f / nrm : 0.0f;
  const float s3 = 1.7320508075688772f;
  const float Y1v0 = s3 * ly * invn;
  const float Y1v1 = s3 * lz * invn;
  const float Y1v2 = s3 * lx * invn;
  const float c  = 0.125f;
  const float cs = 0.125f / s3;
  const bool center = (koff == 62);
  const float inv = 0.17677669529663687f;  // 1/sqrt(32)
  for (int p = tid; p < 16384; p += 256) {
    const int t = p & 7;
    const int l = (p >> 3) & 63;
    const int f = p >> 9;
    const int kb = f >> 3, nt = f & 7;
    const int i = kb*32 + (l >> 4)*8 + t;
    const int j = nt*16 + (l & 15);
    float val;
    if (i < 32) {
      if (j < 32) {
        val = c * W[0][i][j];
        if (center) val += inv * rdf(wscs, i*32 + j, sf);
      } else {
        const int wq = (j - 32) / 3, kk = (j - 32) % 3;
        const float yv = (kk == 0) ? Y1v0 : ((kk == 1) ? Y1v1 : Y1v2);
        val = c * W[1][i][wq] * yv;
      }
    } else {
      const int u = (i - 32) / 3, ii = (i - 32) % 3;
      const float yvi = (ii == 0) ? Y1v0 : ((ii == 1) ? Y1v1 : Y1v2);
      if (j < 32) {
        val = cs * W[3][u][j] * yvi;
      } else {
        const int wq = (j - 32) / 3, kk = (j - 32) % 3;
        val = (ii == kk) ? c * W[2][u][wq] : 0.0f;
        if (center && ii == kk) val += inv * rdf(wscv, u*32 + wq, vf);
      }
    }
    g_kern[koff * 16384 + p] = f2bf(val);
  }
  if (koff == 0 && tid < 128) g_kern[KERN_USH + tid] = 0;  // zero row (idx==N)
}

// --------------------------------------------------------------------------
// Main conv: 512 WGs x 512 thr (8 waves) -> 2 blocks/CU (LDS 64KB each),
// 16 waves/CU (regs <= 128: acc[2][8]=64 AGPR). Wave = 32 dsts x 128 cols
// (no duplicate gathers). Fragment-sparse act-gating. B: GLD16 double
// buffer, ONE barrier/ko; next-ko A gathers issued at kb2/kb3 so they
// drain inside the same vmcnt(0) as the B stage. LDS-bounce epilogue.
// --------------------------------------------------------------------------
__global__ __launch_bounds__(512, 4) void conv_main(
    const unsigned short* __restrict__ xfeat,
    const int* __restrict__ nidx,
    void* __restrict__ out)
{
  __shared__ __align__(16) unsigned short Blds[2][16384];  // 2 x 32 KB
  const int of32 = g_isf32[0];
  const unsigned short* xs = of32 ? g_x : xfeat;
  const int tid = threadIdx.x;
  const int wv = tid >> 6;        // 0..7
  const int l  = tid & 63;
  const int lr = l & 15;
  const int lk = l >> 4;
  const int m0 = blockIdx.x * 256 + wv * 32;   // wave's 32 dsts

  f32x4 acc[2][8];
  #pragma unroll
  for (int i = 0; i < 2; ++i)
    #pragma unroll
    for (int j = 0; j < 8; ++j) acc[i][j] = (f32x4)0.0f;

  const unsigned short* zrow = g_kern + KERN_USH;

  {  // prologue: stage B(0) reg-staged (once)
    const unsigned short* s = g_kern + tid*8;
    short8 p[4];
    #pragma unroll
    for (int c = 0; c < 4; ++c) p[c] = *(const short8*)(s + c*4096);
    #pragma unroll
    for (int c = 0; c < 4; ++c) *(short8*)(&Blds[0][tid*8 + c*4096]) = p[c];
  }

  // prologue: ko=0 masks/pointers + kb0/kb1 gathers; prefetch ko=1 indices
  bool act[2];
  const unsigned short* rp[2];
  {
    const int* ip = nidx + m0;
    #pragma unroll
    for (int mt = 0; mt < 2; ++mt) {
      const int idx = ip[mt*16 + lr];
      const bool valid = (unsigned)idx < (unsigned)NPTS;
      act[mt] = __any(valid);
      rp[mt] = valid ? (xs + (size_t)idx * 128 + lk*8) : (zrow + lk*8);
    }
  }
  short8 a[2][2];
  #pragma unroll
  for (int mt = 0; mt < 2; ++mt)
    if (act[mt]) a[0][mt] = *(const short8*)(rp[mt]);
  #pragma unroll
  for (int mt = 0; mt < 2; ++mt)
    if (act[mt]) a[1][mt] = *(const short8*)(rp[mt] + 32);
  int idxn[2];
  {
    const int* ip = nidx + NPTS + m0;
    #pragma unroll
    for (int mt = 0; mt < 2; ++mt) idxn[mt] = ip[mt*16 + lr];
  }
  __syncthreads();

  int cur = 0;
  for (int ko = 0; ko < NOFF; ++ko) {
    const bool hn  = (ko + 1 < NOFF);
    const bool hn2 = (ko + 2 < NOFF);

    // B(ko+1) direct to LDS[cur^1]; drains at end-of-iter barrier
    if (hn) {
      const unsigned short* s = g_kern + (ko + 1) * 16384 + wv*512 + l*8;
      unsigned short* d = &Blds[cur ^ 1][wv*512];
      #pragma unroll
      for (int c = 0; c < 4; ++c) GLD16(s + c*4096, d + c*4096);
    }
    // indices for ko+2
    int idx2[2];
    if (hn2) {
      const int* ip = nidx + (size_t)(ko + 2) * NPTS + m0;
      #pragma unroll
      for (int mt = 0; mt < 2; ++mt) idx2[mt] = ip[mt*16 + lr];
    }

    bool actn[2];
    const unsigned short* rpn[2];
    #pragma unroll
    for (int kb = 0; kb < 4; ++kb) {
      // MFMA on slot kb&1 (two nt-batches of 4 to cap live B regs)
      #pragma unroll
      for (int h = 0; h < 2; ++h) {
        short8 b[4];
        #pragma unroll
        for (int nt = 0; nt < 4; ++nt)
          b[nt] = *(const short8*)(&Blds[cur][((kb*8 + h*4 + nt)*64 + l)*8]);
        #pragma unroll
        for (int mt = 0; mt < 2; ++mt) {
          if (act[mt]) {
            #pragma unroll
            for (int nt = 0; nt < 4; ++nt)
              acc[mt][h*4 + nt] = __builtin_amdgcn_mfma_f32_16x16x32_bf16(
                  a[kb & 1][mt], b[nt], acc[mt][h*4 + nt], 0, 0, 0);
          }
        }
      }
      // refill the just-consumed slot
      if (kb < 2) {
        #pragma unroll
        for (int mt = 0; mt < 2; ++mt)
          if (act[mt]) a[kb & 1][mt] = *(const short8*)(rp[mt] + (kb + 2)*32);
      } else if (hn) {
        if (kb == 2) {      // next-ko masks + kb0 gather (drains at barrier)
          #pragma unroll
          for (int mt = 0; mt < 2; ++mt) {
            const bool validn = (unsigned)idxn[mt] < (unsigned)NPTS;
            actn[mt] = __any(validn);
            rpn[mt] = validn ? (xs + (size_t)idxn[mt] * 128 + lk*8)
                             : (zrow + lk*8);
            if (actn[mt]) a[0][mt] = *(const short8*)(rpn[mt]);
          }
        } else {            // kb == 3: next-ko kb1 gather
          #pragma unroll
          for (int mt = 0; mt < 2; ++mt)
            if (actn[mt]) a[1][mt] = *(const short8*)(rpn[mt] + 32);
        }
      }
    }

    if (hn) {
      #pragma unroll
      for (int mt = 0; mt < 2; ++mt) { act[mt] = actn[mt]; rp[mt] = rpn[mt]; }
    }
    if (hn2) {
      #pragma unroll
      for (int mt = 0; mt < 2; ++mt) idxn[mt] = idx2[mt];
    }
    __syncthreads();
    cur ^= 1;
  }

  // epilogue
  if (of32) {
    float* of = (float*)out;
    #pragma unroll
    for (int mt = 0; mt < 2; ++mt)
      #pragma unroll
      for (int nt = 0; nt < 8; ++nt)
        #pragma unroll
        for (int r = 0; r < 4; ++r)
          of[(size_t)(m0 + mt*16 + lk*4 + r) * 128 + nt*16 + lr] = acc[mt][nt][r];
  } else {
    // block-wide LDS bounce (XOR-swizzled), then coalesced 16B stores
    unsigned short* eb = &Blds[0][0];   // 64 KB = 256 rows x 128 cols
    #pragma unroll
    for (int mt = 0; mt < 2; ++mt)
      #pragma unroll
      for (int nt = 0; nt < 8; ++nt)
        #pragma unroll
        for (int r = 0; r < 4; ++r) {
          const int row = wv*32 + mt*16 + lk*4 + r;    // 0..255 local
          const int ush = nt*16 + lr;                  // 0..127 in-row
          eb[row*128 + (ush ^ ((row & 7) << 3))] = f2bf(acc[mt][nt][r]);
        }
    __syncthreads();
    unsigned short* ob = (unsigned short*)out;
    const int row = tid >> 1;
    #pragma unroll
    for (int it = 0; it < 8; ++it) {
      const int ub = (tid & 1)*64 + it*8;
      const short8 v = *(const short8*)(&eb[row*128 + (ub ^ ((row & 7) << 3))]);
      *(short8*)(&ob[(size_t)(blockIdx.x*256 + row) * 128 + ub]) = v;
    }
  }
}

extern "C" void kernel_launch(void* const* d_in, const int* in_sizes, int n_in,
                              void* d_out, int out_size, void* d_ws, size_t ws_size,
                              hipStream_t stream) {
  const unsigned short* xfeat  = (const unsigned short*)d_in[0];
  const void*           weight = d_in[1];
  const void*           wscs   = d_in[2];
  const void*           wscv   = d_in[3];
  const int*            nidx   = (const int*)d_in[4];

  hipLaunchKernelGGL(k_detect, dim3(1), dim3(64), 0, stream,
                     (const unsigned short*)d_in[0], (const unsigned short*)d_in[1],
                     (const unsigned short*)d_in[2], (const unsigned short*)d_in[3]);
  hipLaunchKernelGGL(k_convx, dim3(NPTS * 128 / (256 * 8)), dim3(256), 0, stream, d_in[0]);
  hipLaunchKernelGGL(gen_kern, dim3(NOFF), dim3(256), 0, stream, weight, wscs, wscv);
  hipLaunchKernelGGL(conv_main, dim3(NPTS / 256), dim3(512), 0, stream,
                     xfeat, nidx, d_out);
}